// Round 1
// baseline (379.326 us; speedup 1.0000x reference)
//
#include <hip/hip_runtime.h>

#define DIMX 512
#define HEADSX 4
#define DHX 128
#define CHX 16
#define NCX 128
#define SX 2048
#define BX 2
#define BHX 8

__device__ __forceinline__ float sigmoidf_(float z){ return 1.0f/(1.0f + __expf(-z)); }

// ---------------- K1: RMSNorm + per-token adaptive lr ----------------
// grid 4096 (tokens), block 256
__global__ __launch_bounds__(256) void k_rms_lr(const float* __restrict__ seq,
    const float* __restrict__ scale, const float* __restrict__ Wstep,
    float* __restrict__ x, float* __restrict__ lrArr){
  int tok = blockIdx.x; int tid = threadIdx.x;
  const float* row = seq + (size_t)tok*DIMX;
  float v0 = row[tid], v1 = row[tid+256];
  float ss = v0*v0 + v1*v1;
  #pragma unroll
  for (int o=32;o>0;o>>=1) ss += __shfl_down(ss,o,64);
  __shared__ float red[4];
  __shared__ float rs_s;
  int wv = tid>>6, ln = tid&63;
  if (ln==0) red[wv]=ss;
  __syncthreads();
  if (tid==0){
    float ms = (red[0]+red[1]+red[2]+red[3]) * (1.0f/DIMX);
    rs_s = 1.0f/sqrtf(ms + 1e-6f);
  }
  __syncthreads();
  float rs = rs_s;
  float x0 = v0*rs*scale[tid];
  float x1 = v1*rs*scale[tid+256];
  size_t xo = (size_t)tok*DIMX;
  x[xo+tid]=x0; x[xo+tid+256]=x1;
  // lr partials: dot(x_row, Wstep[:,h]) for h=0..3
  float a0 = x0*Wstep[tid*4+0] + x1*Wstep[(tid+256)*4+0];
  float a1 = x0*Wstep[tid*4+1] + x1*Wstep[(tid+256)*4+1];
  float a2 = x0*Wstep[tid*4+2] + x1*Wstep[(tid+256)*4+2];
  float a3 = x0*Wstep[tid*4+3] + x1*Wstep[(tid+256)*4+3];
  #pragma unroll
  for (int o=32;o>0;o>>=1){
    a0 += __shfl_down(a0,o,64); a1 += __shfl_down(a1,o,64);
    a2 += __shfl_down(a2,o,64); a3 += __shfl_down(a3,o,64);
  }
  __shared__ float red4[4][4];
  if (ln==0){ red4[wv][0]=a0; red4[wv][1]=a1; red4[wv][2]=a2; red4[wv][3]=a3; }
  __syncthreads();
  if (tid<4){
    float d = red4[0][tid]+red4[1][tid]+red4[2][tid]+red4[3][tid];
    int b = tok>>11, s = tok&2047;
    lrArr[(size_t)(b*HEADSX+tid)*SX + s] = 0.01f * sigmoidf_(d);
  }
}

// ---------------- K2: per-chunk mean -> mom / (1-dec) ----------------
// grid 256 (b*128+nc), block 64 (1 wave)
__global__ __launch_bounds__(64) void k_stats(const float* __restrict__ x,
    const float* __restrict__ Wmom, const float* __restrict__ Wdec,
    float* __restrict__ momw, float* __restrict__ decw){
  int blk = blockIdx.x; int b = blk>>7, nc = blk&127; int ln = threadIdx.x;
  float am[4]={0,0,0,0}, ad[4]={0,0,0,0};
  const float* base = x + ((size_t)(b*SX + nc*CHX))*DIMX;
  for (int r=0;r<8;r++){
    int d = ln + 64*r;
    float m = 0.0f;
    #pragma unroll
    for (int c=0;c<CHX;c++) m += base[(size_t)c*DIMX + d];
    m *= (1.0f/CHX);
    #pragma unroll
    for (int h=0;h<4;h++){ am[h]+=m*Wmom[d*4+h]; ad[h]+=m*Wdec[d*4+h]; }
  }
  #pragma unroll
  for (int h=0;h<4;h++){
    #pragma unroll
    for (int o=32;o>0;o>>=1){ am[h]+=__shfl_down(am[h],o,64); ad[h]+=__shfl_down(ad[h],o,64); }
  }
  if (ln==0){
    #pragma unroll
    for (int h=0;h<4;h++){
      momw[(b*HEADSX+h)*NCX + nc] = sigmoidf_(am[h]);
      decw[(b*HEADSX+h)*NCX + nc] = 1.0f - sigmoidf_(ad[h]);
    }
  }
}

// ---------------- K3: transpose w1 per bh (for coalesced dpred @ w1^T) ----------------
__global__ __launch_bounds__(256) void k_w1t(const float* __restrict__ w1, float* __restrict__ w1t){
  int bh = blockIdx.x;
  const float* src = w1 + (size_t)bh*DHX*DHX;
  float* dst = w1t + (size_t)bh*DHX*DHX;
  for (int idx=threadIdx.x; idx<DHX*DHX; idx+=256){
    int j = idx>>7, i = idx&127;
    dst[idx] = src[i*DHX + j];   // w1t[j][i] = w1[i][j]
  }
}

// ---------------- K4: k,v projection, stored [bh][t][c][dh] ----------------
// grid 1024 (bh*128+t), block 256: lanes 0..127 -> k cols, 128..255 -> v cols
__global__ __launch_bounds__(256) void k_kv(const float* __restrict__ x, const float* __restrict__ Wkv,
    float* __restrict__ kfac, float* __restrict__ vfac){
  int bt = blockIdx.x; int bh = bt>>7, t = bt&127; int b = bh>>2, h = bh&3;
  __shared__ __align__(16) float xs[DIMX*20];   // [d][c] padded to 20 (16B-aligned rows, 8-way write conflicts only at staging)
  int tid = threadIdx.x;
  const float* xbase = x + ((size_t)(b*SX + t*CHX))*DIMX;
  #pragma unroll
  for (int c=0;c<CHX;c++){
    xs[(tid)*20 + c]     = xbase[(size_t)c*DIMX + tid];
    xs[(tid+256)*20 + c] = xbase[(size_t)c*DIMX + tid+256];
  }
  __syncthreads();
  int p = tid & 127;
  int isv = tid >> 7;                 // 0 = k half, 1 = v half
  int wcol = (isv ? 512 : 0) + h*DHX + p;
  float acc[CHX];
  #pragma unroll
  for (int c=0;c<CHX;c++) acc[c]=0.0f;
  for (int d=0; d<DIMX; d++){
    float w = Wkv[(size_t)d*1024 + wcol];
    const float4* xr = (const float4*)(xs + d*20);   // broadcast reads
    float4 q0 = xr[0], q1 = xr[1], q2 = xr[2], q3 = xr[3];
    acc[0]+=q0.x*w;  acc[1]+=q0.y*w;  acc[2]+=q0.z*w;  acc[3]+=q0.w*w;
    acc[4]+=q1.x*w;  acc[5]+=q1.y*w;  acc[6]+=q1.z*w;  acc[7]+=q1.w*w;
    acc[8]+=q2.x*w;  acc[9]+=q2.y*w;  acc[10]+=q2.z*w; acc[11]+=q2.w*w;
    acc[12]+=q3.x*w; acc[13]+=q3.y*w; acc[14]+=q3.z*w; acc[15]+=q3.w*w;
  }
  float* dst = (isv ? vfac : kfac) + ((size_t)bt*CHX)*DHX + p;
  #pragma unroll
  for (int c=0;c<CHX;c++) dst[(size_t)c*DHX] = acc[c];
}

// ---------------- K5: per-chunk gradient factors ----------------
// grid 1024 (bh*128+t), block 256. Computes a = silu(k@w0), dpred, dh0 = (dpred@w1^T)*silu'(h).
// vfac is overwritten in place with dpred.
__global__ __launch_bounds__(256) void k_grad(const float* __restrict__ kfac, float* __restrict__ vfac,
    float* __restrict__ afac, float* __restrict__ dhfac,
    const float* __restrict__ w0, const float* __restrict__ w1, const float* __restrict__ w1t,
    const float* __restrict__ lrArr){
  int bt = blockIdx.x; int bh = bt>>7, t = bt&127;
  __shared__ float ksv[CHX*DHX];
  __shared__ float asv[CHX*DHX];
  __shared__ float dpsv[CHX*DHX];
  int tid = threadIdx.x;
  size_t cb = (size_t)bt*CHX*DHX;
  #pragma unroll
  for (int r=0;r<8;r++){
    int idx = tid + 256*r;
    ksv[idx]  = kfac[cb+idx];
    dpsv[idx] = vfac[cb+idx];   // currently v
  }
  __syncthreads();
  int p = tid&127, ch = tid>>7;            // thread owns rows c = ch*8..ch*8+7, column p
  const float* w0b  = w0  + (size_t)bh*DHX*DHX;
  const float* w1b  = w1  + (size_t)bh*DHX*DHX;
  const float* w1tb = w1t + (size_t)bh*DHX*DHX;
  float acc[8], sp[8];
  // h = k @ w0 ; a = silu(h) ; keep silu'(h) in regs (same (c,p) mapping reused for da)
  #pragma unroll
  for (int r=0;r<8;r++) acc[r]=0.0f;
  for (int i=0;i<DHX;i++){
    float w = w0b[i*DHX + p];
    #pragma unroll
    for (int r=0;r<8;r++) acc[r] += ksv[(ch*8+r)*DHX + i]*w;
  }
  #pragma unroll
  for (int r=0;r<8;r++){
    float hh = acc[r];
    float sg = sigmoidf_(hh);
    float a  = hh*sg;
    sp[r] = sg*(1.0f + hh*(1.0f-sg));
    asv[(ch*8+r)*DHX + p] = a;
    afac[cb + (ch*8+r)*DHX + p] = a;
  }
  __syncthreads();
  // pred = a @ w1 ; dpred = 2*lr/DH * (pred - v)
  #pragma unroll
  for (int r=0;r<8;r++) acc[r]=0.0f;
  for (int i=0;i<DHX;i++){
    float w = w1b[i*DHX + p];
    #pragma unroll
    for (int r=0;r<8;r++) acc[r] += asv[(ch*8+r)*DHX + i]*w;
  }
  #pragma unroll
  for (int r=0;r<8;r++){
    int c = ch*8+r;
    float lrv = lrArr[(size_t)bh*SX + t*CHX + c];
    float dp = (2.0f/DHX)*lrv*(acc[r] - dpsv[c*DHX+p]);  // own element: safe in-place
    dpsv[c*DHX+p] = dp;
    vfac[cb + c*DHX + p] = dp;
  }
  __syncthreads();
  // da = dpred @ w1^T ; dh0 = da * silu'(h)
  #pragma unroll
  for (int r=0;r<8;r++) acc[r]=0.0f;
  for (int j=0;j<DHX;j++){
    float w = w1tb[j*DHX + p];
    #pragma unroll
    for (int r=0;r<8;r++) acc[r] += dpsv[(ch*8+r)*DHX + j]*w;
  }
  #pragma unroll
  for (int r=0;r<8;r++){
    dhfac[cb + (ch*8+r)*DHX + p] = acc[r]*sp[r];
  }
}

// ---------------- K6: fused momentum + decay scan (s reconstructed from rank-16 factors) ----------------
// grid 256 = 8 bh x 8 jblocks(16) x 4 iblocks(32); block 256; 2 (i,j) elems/thread/path
__global__ __launch_bounds__(256) void k_scan(const float* __restrict__ kfac, const float* __restrict__ afac,
    const float* __restrict__ dhfac, const float* __restrict__ dpfac,
    const float* __restrict__ momw, const float* __restrict__ decw,
    float* __restrict__ out){
  int blk = blockIdx.x;
  int bh = blk>>5; int rest = blk&31; int jb = rest>>2; int ig = rest&3;
  int j0 = jb*16, i0 = ig*32;
  int tid = threadIdx.x;
  int jj = tid&15, g = tid>>4;     // i = i0+g and i0+g+16
  __shared__ float ks[CHX*32], as_[CHX*32], dhs[CHX*16], dps[CHX*16];
  float m0a=0,m0b=0,u0a=0,u0b=0,m1a=0,m1b=0,u1a=0,u1b=0;
  size_t outb0 = ((size_t)bh*NCX)*(DHX*DHX);
  size_t outb1 = ((size_t)(BHX+bh)*NCX)*(DHX*DHX);
  for (int t=0; t<NCX; t++){
    size_t cb = ((size_t)(bh*NCX + t))*CHX*DHX;
    {
      int idx = tid;       int c  = idx>>5,  ii  = idx&31;
      ks[idx]   = kfac[cb + c*DHX  + i0 + ii];
      as_[idx]  = afac[cb + c*DHX  + i0 + ii];
      int idx2 = tid+256;  int c2 = idx2>>5, ii2 = idx2&31;
      ks[idx2]  = kfac[cb + c2*DHX + i0 + ii2];
      as_[idx2] = afac[cb + c2*DHX + i0 + ii2];
      int cc = tid>>4, jl = tid&15;
      dhs[tid] = dhfac[cb + cc*DHX + j0 + jl];
      dps[tid] = dpfac[cb + cc*DHX + j0 + jl];
    }
    __syncthreads();
    float s0a=0,s0b=0,s1a=0,s1b=0;
    #pragma unroll
    for (int c=0;c<CHX;c++){
      float dh = dhs[c*16+jj], dp = dps[c*16+jj];
      float ka = ks[c*32+g],  kb = ks[c*32+g+16];
      float aa = as_[c*32+g], ab = as_[c*32+g+16];
      s0a += ka*dh; s0b += kb*dh;
      s1a += aa*dp; s1b += ab*dp;
    }
    float mo = momw[bh*NCX + t];
    float de = decw[bh*NCX + t];            // already (1 - dec)
    m0a = mo*m0a - s0a; m0b = mo*m0b - s0b; // s = -grad
    m1a = mo*m1a - s1a; m1b = mo*m1b - s1b;
    u0a = de*u0a + m0a; u0b = de*u0b + m0b;
    u1a = de*u1a + m1a; u1b = de*u1b + m1b;
    size_t o = (size_t)t*(DHX*DHX) + (size_t)(i0+g)*DHX + j0 + jj;
    out[outb0 + o]            = u0a;
    out[outb0 + o + 16*DHX]   = u0b;
    out[outb1 + o]            = u1a;
    out[outb1 + o + 16*DHX]   = u1b;
    __syncthreads();
  }
}

extern "C" void kernel_launch(void* const* d_in, const int* in_sizes, int n_in,
                              void* d_out, int out_size, void* d_ws, size_t ws_size,
                              hipStream_t stream) {
  (void)in_sizes; (void)n_in; (void)out_size; (void)ws_size;
  const float* seq   = (const float*)d_in[0];
  const float* scale = (const float*)d_in[1];
  const float* Wkv   = (const float*)d_in[2];
  const float* Wstep = (const float*)d_in[3];
  const float* Wmom  = (const float*)d_in[4];
  const float* Wdec  = (const float*)d_in[5];
  const float* w0    = (const float*)d_in[6];
  const float* w1    = (const float*)d_in[7];
  float* out = (float*)d_out;
  float* ws  = (float*)d_ws;

  // workspace layout (floats)
  float* x     = ws;                       // 2,097,152
  float* kfac  = ws + 2097152;             // 2,097,152
  float* vfac  = ws + 4194304;             // 2,097,152 (becomes dpred in-place)
  float* afac  = ws + 6291456;             // 2,097,152
  float* dhfac = ws + 8388608;             // 2,097,152
  float* w1t   = ws + 10485760;            // 131,072
  float* lrArr = ws + 10616832;            // 16,384
  float* momw  = ws + 10633216;            // 1,024
  float* decw  = ws + 10634240;            // 1,024
  // total 10,635,264 floats = 42.5 MB

  k_rms_lr<<<dim3(BX*SX), dim3(256), 0, stream>>>(seq, scale, Wstep, x, lrArr);
  k_stats<<<dim3(BX*NCX), dim3(64), 0, stream>>>(x, Wmom, Wdec, momw, decw);
  k_w1t<<<dim3(BHX), dim3(256), 0, stream>>>(w1, w1t);
  k_kv<<<dim3(BHX*NCX), dim3(256), 0, stream>>>(x, Wkv, kfac, vfac);
  k_grad<<<dim3(BHX*NCX), dim3(256), 0, stream>>>(kfac, vfac, afac, dhfac, w0, w1, w1t, lrArr);
  k_scan<<<dim3(256), dim3(256), 0, stream>>>(kfac, afac, dhfac, vfac, momw, decw, out);
}

// Round 2
// 334.617 us; speedup vs baseline: 1.1336x; 1.1336x over previous
//
#include <hip/hip_runtime.h>

#define DIMX 512
#define HEADSX 4
#define DHX 128
#define CHX 16
#define NCX 128
#define SX 2048
#define BX 2
#define BHX 8

typedef unsigned short ushort_t;
typedef unsigned int uint_t;
typedef short bf16x8 __attribute__((ext_vector_type(8)));
typedef float f32x4 __attribute__((ext_vector_type(4)));

__device__ __forceinline__ float sigmoidf_(float z){ return 1.0f/(1.0f + __expf(-z)); }

// fp32 -> bf16 round-to-nearest-even
__device__ __forceinline__ ushort_t f2bf(float f){
  uint_t u = __float_as_uint(f);
  return (ushort_t)((u + 0x7FFFu + ((u >> 16) & 1u)) >> 16);
}
__device__ __forceinline__ uint_t pk2(float a, float b){
  return (uint_t)f2bf(a) | ((uint_t)f2bf(b) << 16);
}

#define AS1 __attribute__((address_space(1)))
#define AS3 __attribute__((address_space(3)))
__device__ __forceinline__ void gl_lds16(const void* g, void* l){
#if __has_builtin(__builtin_amdgcn_global_load_lds)
  __builtin_amdgcn_global_load_lds((const AS1 void*)g, (AS3 void*)l, 16, 0, 0);
#else
  // synchronous fallback: same memory semantics, just not async
  *(uint4*)l = *(const uint4*)g;
#endif
}

// ---------------- K1: RMSNorm + per-token adaptive lr ----------------
__global__ __launch_bounds__(256) void k_rms_lr(const float* __restrict__ seq,
    const float* __restrict__ scale, const float* __restrict__ Wstep,
    float* __restrict__ x, float* __restrict__ lrArr){
  int tok = blockIdx.x; int tid = threadIdx.x;
  const float* row = seq + (size_t)tok*DIMX;
  float v0 = row[tid], v1 = row[tid+256];
  float ss = v0*v0 + v1*v1;
  #pragma unroll
  for (int o=32;o>0;o>>=1) ss += __shfl_down(ss,o,64);
  __shared__ float red[4];
  __shared__ float rs_s;
  int wv = tid>>6, ln = tid&63;
  if (ln==0) red[wv]=ss;
  __syncthreads();
  if (tid==0){
    float ms = (red[0]+red[1]+red[2]+red[3]) * (1.0f/DIMX);
    rs_s = 1.0f/sqrtf(ms + 1e-6f);
  }
  __syncthreads();
  float rs = rs_s;
  float x0 = v0*rs*scale[tid];
  float x1 = v1*rs*scale[tid+256];
  size_t xo = (size_t)tok*DIMX;
  x[xo+tid]=x0; x[xo+tid+256]=x1;
  float a0 = x0*Wstep[tid*4+0] + x1*Wstep[(tid+256)*4+0];
  float a1 = x0*Wstep[tid*4+1] + x1*Wstep[(tid+256)*4+1];
  float a2 = x0*Wstep[tid*4+2] + x1*Wstep[(tid+256)*4+2];
  float a3 = x0*Wstep[tid*4+3] + x1*Wstep[(tid+256)*4+3];
  #pragma unroll
  for (int o=32;o>0;o>>=1){
    a0 += __shfl_down(a0,o,64); a1 += __shfl_down(a1,o,64);
    a2 += __shfl_down(a2,o,64); a3 += __shfl_down(a3,o,64);
  }
  __shared__ float red4[4][4];
  if (ln==0){ red4[wv][0]=a0; red4[wv][1]=a1; red4[wv][2]=a2; red4[wv][3]=a3; }
  __syncthreads();
  if (tid<4){
    float d = red4[0][tid]+red4[1][tid]+red4[2][tid]+red4[3][tid];
    int b = tok>>11, s = tok&2047;
    lrArr[(size_t)(b*HEADSX+tid)*SX + s] = 0.01f * sigmoidf_(d);
  }
}

// ---------------- K2: per-chunk mean -> mom / (1-dec) ----------------
__global__ __launch_bounds__(64) void k_stats(const float* __restrict__ x,
    const float* __restrict__ Wmom, const float* __restrict__ Wdec,
    float* __restrict__ momw, float* __restrict__ decw){
  int blk = blockIdx.x; int b = blk>>7, nc = blk&127; int ln = threadIdx.x;
  float am[4]={0,0,0,0}, ad[4]={0,0,0,0};
  const float* base = x + ((size_t)(b*SX + nc*CHX))*DIMX;
  for (int r=0;r<8;r++){
    int d = ln + 64*r;
    float m = 0.0f;
    #pragma unroll
    for (int c=0;c<CHX;c++) m += base[(size_t)c*DIMX + d];
    m *= (1.0f/CHX);
    #pragma unroll
    for (int h=0;h<4;h++){ am[h]+=m*Wmom[d*4+h]; ad[h]+=m*Wdec[d*4+h]; }
  }
  #pragma unroll
  for (int h=0;h<4;h++){
    #pragma unroll
    for (int o=32;o>0;o>>=1){ am[h]+=__shfl_down(am[h],o,64); ad[h]+=__shfl_down(ad[h],o,64); }
  }
  if (ln==0){
    #pragma unroll
    for (int h=0;h<4;h++){
      momw[(b*HEADSX+h)*NCX + nc] = sigmoidf_(am[h]);
      decw[(b*HEADSX+h)*NCX + nc] = 1.0f - sigmoidf_(ad[h]);
    }
  }
}

// ---------------- K3: transpose w1 per bh ----------------
__global__ __launch_bounds__(256) void k_w1t(const float* __restrict__ w1, float* __restrict__ w1t){
  int bh = blockIdx.x;
  const float* src = w1 + (size_t)bh*DHX*DHX;
  float* dst = w1t + (size_t)bh*DHX*DHX;
  for (int idx=threadIdx.x; idx<DHX*DHX; idx+=256){
    int j = idx>>7, i = idx&127;
    dst[idx] = src[i*DHX + j];
  }
}

// ---------------- K4: k,v projection ----------------
// kfac fp32 [bt][c][dh] (for k_grad), vfac fp32 likewise,
// fac0 bf16 rows: [bt*128+p][ k c0..15 | a c0..15 ]  (k part written here)
__global__ __launch_bounds__(256) void k_kv(const float* __restrict__ x, const float* __restrict__ Wkv,
    float* __restrict__ kfac, float* __restrict__ vfac, ushort_t* __restrict__ fac0){
  int bt = blockIdx.x; int bh = bt>>7, t = bt&127; int b = bh>>2, h = bh&3; (void)t;
  __shared__ __align__(16) float xs[DIMX*20];
  int tid = threadIdx.x;
  const float* xbase = x + ((size_t)((bh>>2)*SX + (bt&127)*CHX))*DIMX; (void)b;
  #pragma unroll
  for (int c=0;c<CHX;c++){
    xs[(tid)*20 + c]     = xbase[(size_t)c*DIMX + tid];
    xs[(tid+256)*20 + c] = xbase[(size_t)c*DIMX + tid+256];
  }
  __syncthreads();
  int p = tid & 127;
  int isv = tid >> 7;
  int wcol = (isv ? 512 : 0) + h*DHX + p;
  float acc[CHX];
  #pragma unroll
  for (int c=0;c<CHX;c++) acc[c]=0.0f;
  for (int d=0; d<DIMX; d++){
    float w = Wkv[(size_t)d*1024 + wcol];
    const float4* xr = (const float4*)(xs + d*20);
    float4 q0 = xr[0], q1 = xr[1], q2 = xr[2], q3 = xr[3];
    acc[0]+=q0.x*w;  acc[1]+=q0.y*w;  acc[2]+=q0.z*w;  acc[3]+=q0.w*w;
    acc[4]+=q1.x*w;  acc[5]+=q1.y*w;  acc[6]+=q1.z*w;  acc[7]+=q1.w*w;
    acc[8]+=q2.x*w;  acc[9]+=q2.y*w;  acc[10]+=q2.z*w; acc[11]+=q2.w*w;
    acc[12]+=q3.x*w; acc[13]+=q3.y*w; acc[14]+=q3.z*w; acc[15]+=q3.w*w;
  }
  float* dst = (isv ? vfac : kfac) + ((size_t)bt*CHX)*DHX + p;
  #pragma unroll
  for (int c=0;c<CHX;c++) dst[(size_t)c*DHX] = acc[c];
  if (!isv){
    // bf16 transposed row: fac0[(bt*128+p)*32 + c], c = 0..15
    uint4 q0, q1;
    q0.x = pk2(acc[0],acc[1]);   q0.y = pk2(acc[2],acc[3]);
    q0.z = pk2(acc[4],acc[5]);   q0.w = pk2(acc[6],acc[7]);
    q1.x = pk2(acc[8],acc[9]);   q1.y = pk2(acc[10],acc[11]);
    q1.z = pk2(acc[12],acc[13]); q1.w = pk2(acc[14],acc[15]);
    uint4* dk = (uint4*)(fac0 + ((size_t)bt*128 + p)*32);
    dk[0] = q0; dk[1] = q1;
  }
}

// ---------------- K5: per-chunk gradient factors (bf16 transposed out) ----------------
// fac0 row p gets a (offset 16); fac1 row p gets dh0 (offset 0) and dpred (offset 16)
__global__ __launch_bounds__(256) void k_grad(const float* __restrict__ kfac, const float* __restrict__ vfac,
    ushort_t* __restrict__ fac0, ushort_t* __restrict__ fac1,
    const float* __restrict__ w0, const float* __restrict__ w1, const float* __restrict__ w1t,
    const float* __restrict__ lrArr){
  int bt = blockIdx.x; int bh = bt>>7, t = bt&127;
  __shared__ float ksv[CHX*DHX];
  __shared__ float asv[CHX*DHX];
  __shared__ float dpsv[CHX*DHX];
  int tid = threadIdx.x;
  size_t cb = (size_t)bt*CHX*DHX;
  #pragma unroll
  for (int r=0;r<8;r++){
    int idx = tid + 256*r;
    ksv[idx]  = kfac[cb+idx];
    dpsv[idx] = vfac[cb+idx];   // currently v
  }
  __syncthreads();
  int p = tid&127, ch = tid>>7;
  const float* w0b  = w0  + (size_t)bh*DHX*DHX;
  const float* w1b  = w1  + (size_t)bh*DHX*DHX;
  const float* w1tb = w1t + (size_t)bh*DHX*DHX;
  size_t rowbase = ((size_t)bt*128 + p)*32;   // ushort index of transposed row
  float acc[8], sp[8];
  // h = k @ w0 ; a = silu(h)
  #pragma unroll
  for (int r=0;r<8;r++) acc[r]=0.0f;
  for (int i=0;i<DHX;i++){
    float w = w0b[i*DHX + p];
    #pragma unroll
    for (int r=0;r<8;r++) acc[r] += ksv[(ch*8+r)*DHX + i]*w;
  }
  float av[8];
  #pragma unroll
  for (int r=0;r<8;r++){
    float hh = acc[r];
    float sg = sigmoidf_(hh);
    float a  = hh*sg;
    sp[r] = sg*(1.0f + hh*(1.0f-sg));
    asv[(ch*8+r)*DHX + p] = a;
    av[r] = a;
  }
  {
    uint4 q; q.x=pk2(av[0],av[1]); q.y=pk2(av[2],av[3]); q.z=pk2(av[4],av[5]); q.w=pk2(av[6],av[7]);
    *(uint4*)(fac0 + rowbase + 16 + ch*8) = q;
  }
  __syncthreads();
  // pred = a @ w1 ; dpred = 2*lr/DH * (pred - v)
  #pragma unroll
  for (int r=0;r<8;r++) acc[r]=0.0f;
  for (int i=0;i<DHX;i++){
    float w = w1b[i*DHX + p];
    #pragma unroll
    for (int r=0;r<8;r++) acc[r] += asv[(ch*8+r)*DHX + i]*w;
  }
  float dpv[8];
  #pragma unroll
  for (int r=0;r<8;r++){
    int c = ch*8+r;
    float lrv = lrArr[(size_t)bh*SX + t*CHX + c];
    float dp = (2.0f/DHX)*lrv*(acc[r] - dpsv[c*DHX+p]);
    dpsv[c*DHX+p] = dp;
    dpv[r] = dp;
  }
  {
    uint4 q; q.x=pk2(dpv[0],dpv[1]); q.y=pk2(dpv[2],dpv[3]); q.z=pk2(dpv[4],dpv[5]); q.w=pk2(dpv[6],dpv[7]);
    *(uint4*)(fac1 + rowbase + 16 + ch*8) = q;
  }
  __syncthreads();
  // da = dpred @ w1^T ; dh0 = da * silu'(h)
  #pragma unroll
  for (int r=0;r<8;r++) acc[r]=0.0f;
  for (int j=0;j<DHX;j++){
    float w = w1tb[j*DHX + p];
    #pragma unroll
    for (int r=0;r<8;r++) acc[r] += dpsv[(ch*8+r)*DHX + j]*w;
  }
  float dhv[8];
  #pragma unroll
  for (int r=0;r<8;r++) dhv[r] = acc[r]*sp[r];
  {
    uint4 q; q.x=pk2(dhv[0],dhv[1]); q.y=pk2(dhv[2],dhv[3]); q.z=pk2(dhv[4],dhv[5]); q.w=pk2(dhv[6],dhv[7]);
    *(uint4*)(fac1 + rowbase + ch*8) = q;
  }
}

// ---------------- K6: MFMA scan ----------------
// 512 blocks = (rest 0..63: ig*8+jb) * 8 bh  (bh = blk&7 for XCD L2 locality)
// 128 threads = wave0 (path0: k x dh0) + wave1 (path1: a x dpred)
__global__ __launch_bounds__(128) void k_scan(const ushort_t* __restrict__ fac0,
    const ushort_t* __restrict__ fac1,
    const float* __restrict__ momw, const float* __restrict__ decw,
    float* __restrict__ out){
  int blk = blockIdx.x;
  int bh = blk & 7; int rest = blk >> 3;     // 0..63
  int ig = rest >> 3, jb = rest & 7;
  int i0 = ig*16, j0 = jb*16;
  int tid = threadIdx.x;
  int wv = tid >> 6, lane = tid & 63;
  int quad = lane >> 4, rrow = lane & 15;
  __shared__ __align__(16) ushort_t sbuf[2][1024];   // [buf][ fac0 slice 512 | fac1 slice 512 ]
  // global slice base for this wave (ushort units); per-t stride = 128*32 = 4096
  const ushort_t* gsl = (wv==0)
      ? fac0 + ((size_t)bh*NCX*128 + (size_t)i0)*32
      : fac1 + ((size_t)bh*NCX*128 + (size_t)j0)*32;

  f32x4 m_ = {0.f,0.f,0.f,0.f};
  f32x4 u_ = {0.f,0.f,0.f,0.f};
  const f32x4 zero = {0.f,0.f,0.f,0.f};
  size_t obase = ((size_t)(wv*BHX + bh)*NCX)*((size_t)DHX*DHX) + (size_t)i0*DHX + j0;
  const float* mop = momw + bh*NCX;
  const float* dep = decw + bh*NCX;

  // preload t=0
  gl_lds16((const void*)(gsl + (size_t)lane*8), (void*)&sbuf[0][wv*512]);
  __syncthreads();
  int b = 0;
  for (int t=0; t<NCX; t++){
    if (t+1 < NCX)
      gl_lds16((const void*)(gsl + (size_t)(t+1)*4096 + (size_t)lane*8),
               (void*)&sbuf[b^1][wv*512]);
    float mo = mop[t], de = dep[t];
    bf16x8 fa = {0,0,0,0,0,0,0,0};
    bf16x8 fb = {0,0,0,0,0,0,0,0};
    if (quad < 2){
      fa = *(const bf16x8*)&sbuf[b][      rrow*32 + wv*16 + quad*8];
      fb = *(const bf16x8*)&sbuf[b][512 + rrow*32 + wv*16 + quad*8];
    }
    f32x4 g = __builtin_amdgcn_mfma_f32_16x16x32_bf16(fa, fb, zero, 0, 0, 0);
    size_t ob = obase + (size_t)t*(DHX*DHX);
    #pragma unroll
    for (int r=0;r<4;r++){
      m_[r] = mo*m_[r] - g[r];
      u_[r] = de*u_[r] + m_[r];
      out[ob + (size_t)(quad*4+r)*DHX + rrow] = u_[r];
    }
    __syncthreads();
    b ^= 1;
  }
}

extern "C" void kernel_launch(void* const* d_in, const int* in_sizes, int n_in,
                              void* d_out, int out_size, void* d_ws, size_t ws_size,
                              hipStream_t stream) {
  (void)in_sizes; (void)n_in; (void)out_size; (void)ws_size;
  const float* seq   = (const float*)d_in[0];
  const float* scale = (const float*)d_in[1];
  const float* Wkv   = (const float*)d_in[2];
  const float* Wstep = (const float*)d_in[3];
  const float* Wmom  = (const float*)d_in[4];
  const float* Wdec  = (const float*)d_in[5];
  const float* w0    = (const float*)d_in[6];
  const float* w1    = (const float*)d_in[7];
  float* out = (float*)d_out;
  float* ws  = (float*)d_ws;

  // workspace layout (float units)
  float*    x     = ws;                      // 2,097,152
  float*    kfac  = ws + 2097152;            // 2,097,152
  float*    vfac  = ws + 4194304;            // 2,097,152
  ushort_t* fac0  = (ushort_t*)(ws + 6291456);  // 4,194,304 ushorts (= 2,097,152 floats)
  ushort_t* fac1  = (ushort_t*)(ws + 8388608);  // 4,194,304 ushorts
  float*    w1t   = ws + 10485760;           // 131,072
  float*    lrArr = ws + 10616832;           // 16,384
  float*    momw  = ws + 10633216;           // 1,024
  float*    decw  = ws + 10634240;           // 1,024

  k_rms_lr<<<dim3(BX*SX), dim3(256), 0, stream>>>(seq, scale, Wstep, x, lrArr);
  k_stats<<<dim3(BX*NCX), dim3(64), 0, stream>>>(x, Wmom, Wdec, momw, decw);
  k_w1t<<<dim3(BHX), dim3(256), 0, stream>>>(w1, w1t);
  k_kv<<<dim3(BHX*NCX), dim3(256), 0, stream>>>(x, Wkv, kfac, vfac, fac0);
  k_grad<<<dim3(BHX*NCX), dim3(256), 0, stream>>>(kfac, vfac, fac0, fac1, w0, w1, w1t, lrArr);
  k_scan<<<dim3(512), dim3(128), 0, stream>>>(fac0, fac1, momw, decw, out);
}

// Round 3
// 255.147 us; speedup vs baseline: 1.4867x; 1.3115x over previous
//
#include <hip/hip_runtime.h>

#define DIMX 512
#define HEADSX 4
#define DHX 128
#define CHX 16
#define NCX 128
#define SX 2048
#define BX 2
#define BHX 8
#define PADX 520   // xs LDS row pad (ushorts): banks (4c + kk/2) -> worst 2-way (free)
#define PADF 136   // factor LDS row pad (ushorts): same property

typedef unsigned short ushort_t;
typedef unsigned int uint_t;
typedef short bf16x8 __attribute__((ext_vector_type(8)));
typedef float f32x4 __attribute__((ext_vector_type(4)));

__device__ __forceinline__ float sigmoidf_(float z){ return 1.0f/(1.0f + __expf(-z)); }

// fp32 -> bf16 round-to-nearest-even
__device__ __forceinline__ ushort_t f2bf(float f){
  uint_t u = __float_as_uint(f);
  return (ushort_t)((u + 0x7FFFu + ((u >> 16) & 1u)) >> 16);
}
__device__ __forceinline__ uint_t pk2(float a, float b){
  return (uint_t)f2bf(a) | ((uint_t)f2bf(b) << 16);
}

#define AS1 __attribute__((address_space(1)))
#define AS3 __attribute__((address_space(3)))
__device__ __forceinline__ void gl_lds16(const void* g, void* l){
#if __has_builtin(__builtin_amdgcn_global_load_lds)
  __builtin_amdgcn_global_load_lds((const AS1 void*)g, (AS3 void*)l, 16, 0, 0);
#else
  *(uint4*)l = *(const uint4*)g;
#endif
}

// ---------------- K1: RMSNorm + per-token adaptive lr ----------------
__global__ __launch_bounds__(256) void k_rms_lr(const float* __restrict__ seq,
    const float* __restrict__ scale, const float* __restrict__ Wstep,
    float* __restrict__ x, float* __restrict__ lrArr){
  int tok = blockIdx.x; int tid = threadIdx.x;
  const float* row = seq + (size_t)tok*DIMX;
  float v0 = row[tid], v1 = row[tid+256];
  float ss = v0*v0 + v1*v1;
  #pragma unroll
  for (int o=32;o>0;o>>=1) ss += __shfl_down(ss,o,64);
  __shared__ float red[4];
  __shared__ float rs_s;
  int wv = tid>>6, ln = tid&63;
  if (ln==0) red[wv]=ss;
  __syncthreads();
  if (tid==0){
    float ms = (red[0]+red[1]+red[2]+red[3]) * (1.0f/DIMX);
    rs_s = 1.0f/sqrtf(ms + 1e-6f);
  }
  __syncthreads();
  float rs = rs_s;
  float x0 = v0*rs*scale[tid];
  float x1 = v1*rs*scale[tid+256];
  size_t xo = (size_t)tok*DIMX;
  x[xo+tid]=x0; x[xo+tid+256]=x1;
  float a0 = x0*Wstep[tid*4+0] + x1*Wstep[(tid+256)*4+0];
  float a1 = x0*Wstep[tid*4+1] + x1*Wstep[(tid+256)*4+1];
  float a2 = x0*Wstep[tid*4+2] + x1*Wstep[(tid+256)*4+2];
  float a3 = x0*Wstep[tid*4+3] + x1*Wstep[(tid+256)*4+3];
  #pragma unroll
  for (int o=32;o>0;o>>=1){
    a0 += __shfl_down(a0,o,64); a1 += __shfl_down(a1,o,64);
    a2 += __shfl_down(a2,o,64); a3 += __shfl_down(a3,o,64);
  }
  __shared__ float red4[4][4];
  if (ln==0){ red4[wv][0]=a0; red4[wv][1]=a1; red4[wv][2]=a2; red4[wv][3]=a3; }
  __syncthreads();
  if (tid<4){
    float d = red4[0][tid]+red4[1][tid]+red4[2][tid]+red4[3][tid];
    int b = tok>>11, s = tok&2047;
    lrArr[(size_t)(b*HEADSX+tid)*SX + s] = 0.01f * sigmoidf_(d);
  }
}

// ---------------- K2: per-chunk mean -> mom / (1-dec) ----------------
__global__ __launch_bounds__(64) void k_stats(const float* __restrict__ x,
    const float* __restrict__ Wmom, const float* __restrict__ Wdec,
    float* __restrict__ momw, float* __restrict__ decw){
  int blk = blockIdx.x; int b = blk>>7, nc = blk&127; int ln = threadIdx.x;
  float am[4]={0,0,0,0}, ad[4]={0,0,0,0};
  const float* base = x + ((size_t)(b*SX + nc*CHX))*DIMX;
  for (int r=0;r<8;r++){
    int d = ln + 64*r;
    float m = 0.0f;
    #pragma unroll
    for (int c=0;c<CHX;c++) m += base[(size_t)c*DIMX + d];
    m *= (1.0f/CHX);
    #pragma unroll
    for (int h=0;h<4;h++){ am[h]+=m*Wmom[d*4+h]; ad[h]+=m*Wdec[d*4+h]; }
  }
  #pragma unroll
  for (int h=0;h<4;h++){
    #pragma unroll
    for (int o=32;o>0;o>>=1){ am[h]+=__shfl_down(am[h],o,64); ad[h]+=__shfl_down(ad[h],o,64); }
  }
  if (ln==0){
    #pragma unroll
    for (int h=0;h<4;h++){
      momw[(b*HEADSX+h)*NCX + nc] = sigmoidf_(am[h]);
      decw[(b*HEADSX+h)*NCX + nc] = 1.0f - sigmoidf_(ad[h]);
    }
  }
}

// ---------------- K-prep: bf16 weight layouts ----------------
// blk<64: WkvT[h][kt][col 0..255][kk 0..31], col<128 -> k col h*128+col, else v col 512+h*128+(col-128)
// blk>=64: per-bh w0T[n][k]=w0[k][n], w1T[n][k]=w1[k][n], w1n natural
__global__ __launch_bounds__(256) void k_prep(const float* __restrict__ Wkv,
    const float* __restrict__ w0, const float* __restrict__ w1,
    ushort_t* __restrict__ WkvT, ushort_t* __restrict__ w0T,
    ushort_t* __restrict__ w1T, ushort_t* __restrict__ w1n){
  int blk = blockIdx.x; int tid = threadIdx.x;
  if (blk < 64){
    int h = blk >> 4, kt = blk & 15;
    for (int i=tid; i<8192; i+=256){
      int kk = i >> 8, col = i & 255;
      int wcol = (col < 128) ? (h*128 + col) : (384 + h*128 + col);
      float v = Wkv[(size_t)(kt*32+kk)*1024 + wcol];
      WkvT[(((size_t)h*16 + kt)*256 + col)*32 + kk] = f2bf(v);
    }
  } else {
    int bh = blk - 64;
    size_t base = (size_t)bh*16384;
    for (int i=tid; i<16384; i+=256){
      int r = i >> 7, c = i & 127;
      w0T[base + i] = f2bf(w0[base + (size_t)c*128 + r]);
      w1T[base + i] = f2bf(w1[base + (size_t)c*128 + r]);
      w1n[base + i] = f2bf(w1[base + i]);
    }
  }
}

// ---------------- K-fused: kv projection + per-chunk gradient factors, all MFMA ----------------
// 1024 blocks: bh = blk&7 (XCD L2 locality), t = blk>>3. 256 threads = 4 waves.
// Wave w owns n-tiles {2w,2w+1} in the 128-wide gemms; in the kv gemm it owns
// k-tiles {2w,2w+1} and v-tiles {8+2w,9+2w} so v stays in matching C-registers.
__global__ __launch_bounds__(256) void k_fused(const float* __restrict__ x,
    const ushort_t* __restrict__ WkvT, const ushort_t* __restrict__ w0T,
    const ushort_t* __restrict__ w1T, const ushort_t* __restrict__ w1n,
    const float* __restrict__ lrArr,
    ushort_t* __restrict__ fac0, ushort_t* __restrict__ fac1){
  int blk = blockIdx.x;
  int bh = blk & 7, t = blk >> 3;
  int b = bh >> 2, h = bh & 3;
  int bt = bh*NCX + t;
  __shared__ __align__(16) ushort_t xs[16*PADX];
  __shared__ __align__(16) ushort_t ks[16*PADF];
  __shared__ __align__(16) ushort_t as_[16*PADF];
  __shared__ __align__(16) ushort_t dp_[16*PADF];
  __shared__ __align__(16) ushort_t dh_[16*PADF];
  int tid = threadIdx.x;
  int wv = tid>>6, lane = tid&63;
  int quad = lane>>4, nl = lane&15;
  const f32x4 zero = {0.f,0.f,0.f,0.f};

  // stage x chunk (16x512) as bf16
  const float* xb = x + ((size_t)(b*SX + t*CHX))*DIMX;
  #pragma unroll
  for (int it=0; it<8; it++){
    int f = tid + 256*it;            // float4 index, 2048 total
    int c = f >> 7, k4 = f & 127;
    float4 q = ((const float4*)xb)[(size_t)c*128 + k4];
    uint2 u; u.x = pk2(q.x,q.y); u.y = pk2(q.z,q.w);
    *(uint2*)&xs[c*PADX + k4*4] = u;
  }
  __syncthreads();

  // ---- KV gemm: M=16 (c), N=256 (k|v cols), K=512
  f32x4 kacc[2] = {zero, zero};
  f32x4 vacc[2] = {zero, zero};
  const ushort_t* wkvh = WkvT + (size_t)h*16*256*32;
  for (int kt=0; kt<16; kt++){
    bf16x8 Af = *(const bf16x8*)&xs[nl*PADX + kt*32 + quad*8];
    #pragma unroll
    for (int s=0; s<2; s++){
      int ktile = 2*wv + s;
      bf16x8 Bk = *(const bf16x8*)&wkvh[((size_t)kt*256 + (ktile*16+nl))*32 + quad*8];
      kacc[s] = __builtin_amdgcn_mfma_f32_16x16x32_bf16(Af, Bk, kacc[s], 0,0,0);
      int vtile = 8 + 2*wv + s;
      bf16x8 Bv = *(const bf16x8*)&wkvh[((size_t)kt*256 + (vtile*16+nl))*32 + quad*8];
      vacc[s] = __builtin_amdgcn_mfma_f32_16x16x32_bf16(Af, Bv, vacc[s], 0,0,0);
    }
  }
  // k -> LDS bf16 (element (c=quad*4+r, p=32wv+16s+nl))
  #pragma unroll
  for (int s=0;s<2;s++){
    #pragma unroll
    for (int r=0;r<4;r++)
      ks[(quad*4+r)*PADF + 32*wv + 16*s + nl] = f2bf(kacc[s][r]);
  }
  __syncthreads();

  // ---- gemm1: h = k @ w0   (B = w0T[n=p][k=i])
  const ushort_t* w0b = w0T + (size_t)bh*16384;
  f32x4 hacc[2] = {zero, zero};
  for (int kt=0; kt<4; kt++){
    bf16x8 Af = *(const bf16x8*)&ks[nl*PADF + kt*32 + quad*8];
    #pragma unroll
    for (int s=0; s<2; s++){
      int n0 = (2*wv+s)*16;
      bf16x8 Bf = *(const bf16x8*)&w0b[(size_t)(n0+nl)*128 + kt*32 + quad*8];
      hacc[s] = __builtin_amdgcn_mfma_f32_16x16x32_bf16(Af, Bf, hacc[s], 0,0,0);
    }
  }
  float sp[2][4];
  #pragma unroll
  for (int s=0;s<2;s++){
    #pragma unroll
    for (int r=0;r<4;r++){
      float hh = hacc[s][r];
      float sg = sigmoidf_(hh);
      float a  = hh*sg;
      sp[s][r] = sg*(1.0f + hh*(1.0f-sg));
      as_[(quad*4+r)*PADF + 32*wv + 16*s + nl] = f2bf(a);
    }
  }
  __syncthreads();

  // ---- gemm2: pred = a @ w1   (B = w1T[n=p][k=i]) ; dpred = 2/DH * lr * (pred - v)
  const ushort_t* w1tb = w1T + (size_t)bh*16384;
  f32x4 pacc[2] = {zero, zero};
  for (int kt=0; kt<4; kt++){
    bf16x8 Af = *(const bf16x8*)&as_[nl*PADF + kt*32 + quad*8];
    #pragma unroll
    for (int s=0; s<2; s++){
      int n0 = (2*wv+s)*16;
      bf16x8 Bf = *(const bf16x8*)&w1tb[(size_t)(n0+nl)*128 + kt*32 + quad*8];
      pacc[s] = __builtin_amdgcn_mfma_f32_16x16x32_bf16(Af, Bf, pacc[s], 0,0,0);
    }
  }
  float lrv[4];
  #pragma unroll
  for (int r=0;r<4;r++) lrv[r] = lrArr[(size_t)bh*SX + t*CHX + quad*4 + r];
  #pragma unroll
  for (int s=0;s<2;s++){
    #pragma unroll
    for (int r=0;r<4;r++){
      float dp = (2.0f/DHX)*lrv[r]*(pacc[s][r] - vacc[s][r]);
      dp_[(quad*4+r)*PADF + 32*wv + 16*s + nl] = f2bf(dp);
    }
  }
  __syncthreads();

  // ---- gemm3: da = dpred @ w1^T  (B = w1 natural [n=j][k=p]) ; dh0 = da * silu'(h)
  const ushort_t* w1nb = w1n + (size_t)bh*16384;
  f32x4 dacc[2] = {zero, zero};
  for (int kt=0; kt<4; kt++){
    bf16x8 Af = *(const bf16x8*)&dp_[nl*PADF + kt*32 + quad*8];
    #pragma unroll
    for (int s=0; s<2; s++){
      int n0 = (2*wv+s)*16;
      bf16x8 Bf = *(const bf16x8*)&w1nb[(size_t)(n0+nl)*128 + kt*32 + quad*8];
      dacc[s] = __builtin_amdgcn_mfma_f32_16x16x32_bf16(Af, Bf, dacc[s], 0,0,0);
    }
  }
  #pragma unroll
  for (int s=0;s<2;s++){
    #pragma unroll
    for (int r=0;r<4;r++)
      dh_[(quad*4+r)*PADF + 32*wv + 16*s + nl] = f2bf(dacc[s][r]*sp[s][r]);
  }
  __syncthreads();

  // ---- pack: fac0 row p = {k c0..15 | a c0..15}, fac1 row p = {dh c0..15 | dp c0..15}
  {
    int p = tid & 127, which = tid >> 7;
    const ushort_t* s0 = which ? dh_ : ks;
    const ushort_t* s1 = which ? dp_ : as_;
    ushort_t rowv[32];
    #pragma unroll
    for (int c=0;c<16;c++){ rowv[c] = s0[c*PADF + p]; rowv[16+c] = s1[c*PADF + p]; }
    ushort_t* dst = (which ? fac1 : fac0) + ((size_t)bt*128 + p)*32;
    const uint4* rv = (const uint4*)rowv;
    uint4* dq = (uint4*)dst;
    dq[0]=rv[0]; dq[1]=rv[1]; dq[2]=rv[2]; dq[3]=rv[3];
  }
}

// ---------------- K6: MFMA scan (unchanged from R2) ----------------
__global__ __launch_bounds__(128) void k_scan(const ushort_t* __restrict__ fac0,
    const ushort_t* __restrict__ fac1,
    const float* __restrict__ momw, const float* __restrict__ decw,
    float* __restrict__ out){
  int blk = blockIdx.x;
  int bh = blk & 7; int rest = blk >> 3;
  int ig = rest >> 3, jb = rest & 7;
  int i0 = ig*16, j0 = jb*16;
  int tid = threadIdx.x;
  int wv = tid >> 6, lane = tid & 63;
  int quad = lane >> 4, rrow = lane & 15;
  __shared__ __align__(16) ushort_t sbuf[2][1024];
  const ushort_t* gsl = (wv==0)
      ? fac0 + ((size_t)bh*NCX*128 + (size_t)i0)*32
      : fac1 + ((size_t)bh*NCX*128 + (size_t)j0)*32;

  f32x4 m_ = {0.f,0.f,0.f,0.f};
  f32x4 u_ = {0.f,0.f,0.f,0.f};
  const f32x4 zero = {0.f,0.f,0.f,0.f};
  size_t obase = ((size_t)(wv*BHX + bh)*NCX)*((size_t)DHX*DHX) + (size_t)i0*DHX + j0;
  const float* mop = momw + bh*NCX;
  const float* dep = decw + bh*NCX;

  gl_lds16((const void*)(gsl + (size_t)lane*8), (void*)&sbuf[0][wv*512]);
  __syncthreads();
  int b = 0;
  for (int t=0; t<NCX; t++){
    if (t+1 < NCX)
      gl_lds16((const void*)(gsl + (size_t)(t+1)*4096 + (size_t)lane*8),
               (void*)&sbuf[b^1][wv*512]);
    float mo = mop[t], de = dep[t];
    bf16x8 fa = {0,0,0,0,0,0,0,0};
    bf16x8 fb = {0,0,0,0,0,0,0,0};
    if (quad < 2){
      fa = *(const bf16x8*)&sbuf[b][      rrow*32 + wv*16 + quad*8];
      fb = *(const bf16x8*)&sbuf[b][512 + rrow*32 + wv*16 + quad*8];
    }
    f32x4 g = __builtin_amdgcn_mfma_f32_16x16x32_bf16(fa, fb, zero, 0, 0, 0);
    size_t ob = obase + (size_t)t*(DHX*DHX);
    #pragma unroll
    for (int r=0;r<4;r++){
      m_[r] = mo*m_[r] - g[r];
      u_[r] = de*u_[r] + m_[r];
      out[ob + (size_t)(quad*4+r)*DHX + rrow] = u_[r];
    }
    __syncthreads();
    b ^= 1;
  }
}

extern "C" void kernel_launch(void* const* d_in, const int* in_sizes, int n_in,
                              void* d_out, int out_size, void* d_ws, size_t ws_size,
                              hipStream_t stream) {
  (void)in_sizes; (void)n_in; (void)out_size; (void)ws_size;
  const float* seq   = (const float*)d_in[0];
  const float* scale = (const float*)d_in[1];
  const float* Wkv   = (const float*)d_in[2];
  const float* Wstep = (const float*)d_in[3];
  const float* Wmom  = (const float*)d_in[4];
  const float* Wdec  = (const float*)d_in[5];
  const float* w0    = (const float*)d_in[6];
  const float* w1    = (const float*)d_in[7];
  float* out = (float*)d_out;
  float* ws  = (float*)d_ws;

  // workspace layout (float units)
  float*    x     = ws;                          // 2,097,152
  ushort_t* fac0  = (ushort_t*)(ws + 2097152);   // 4,194,304 ushorts
  ushort_t* fac1  = (ushort_t*)(ws + 4194304);   // 4,194,304 ushorts
  ushort_t* WkvT  = (ushort_t*)(ws + 6291456);   // 524,288 ushorts
  ushort_t* w0T   = (ushort_t*)(ws + 6553600);   // 131,072 ushorts
  ushort_t* w1T   = (ushort_t*)(ws + 6619136);   // 131,072 ushorts
  ushort_t* w1n   = (ushort_t*)(ws + 6684672);   // 131,072 ushorts
  float*    lrArr = ws + 6750208;                // 16,384
  float*    momw  = ws + 6766592;                // 1,024
  float*    decw  = ws + 6767616;                // 1,024

  k_prep<<<dim3(72), dim3(256), 0, stream>>>(Wkv, w0, w1, WkvT, w0T, w1T, w1n);
  k_rms_lr<<<dim3(BX*SX), dim3(256), 0, stream>>>(seq, scale, Wstep, x, lrArr);
  k_stats<<<dim3(BX*NCX), dim3(64), 0, stream>>>(x, Wmom, Wdec, momw, decw);
  k_fused<<<dim3(BHX*NCX), dim3(256), 0, stream>>>(x, WkvT, w0T, w1T, w1n, lrArr, fac0, fac1);
  k_scan<<<dim3(512), dim3(128), 0, stream>>>(fac0, fac1, momw, decw, out);
}